// Round 2
// baseline (248.165 us; speedup 1.0000x reference)
//
#include <hip/hip_runtime.h>
#include <hip/hip_bf16.h>

typedef __attribute__((ext_vector_type(8))) short short8;
typedef __attribute__((ext_vector_type(4))) float floatx4;
typedef __attribute__((ext_vector_type(16))) float floatx16;

__device__ __forceinline__ float bf2f(ushort u) {
    return __uint_as_float(((unsigned int)u) << 16);
}
__device__ __forceinline__ ushort f2bf(float f) {
    unsigned int u = __float_as_uint(f);
    unsigned int r = (u + 0x7FFFu + ((u >> 16) & 1u)) >> 16;
    return (ushort)r;
}
// packed f32x2 -> bf16x2
__device__ __forceinline__ unsigned int pk2(float a, float b) {
    union { __hip_bfloat162 h; unsigned int u; } cv;
    cv.h = __float22bfloat162_rn(make_float2(a, b));
    return cv.u;
}
__device__ __forceinline__ float scrub(float v, float lim) {
    return fminf(fmaxf(v, -lim), lim);
}
// async global->LDS, 16B per lane (lane i lands at wave-uniform lds base + 16*i)
__device__ __forceinline__ void glds16(const ushort* g, ushort* l) {
    __builtin_amdgcn_global_load_lds((const __attribute__((address_space(1))) void*)g,
                                     (__attribute__((address_space(3))) void*)l, 16, 0, 0);
}

// Wave-uniform dtype probe on x: bf16 N(0,1) data has exponent byte in [117,131]
// ~99% at even ushort indices; fp32-as-ushort gives ~6%. 32 samples, thr 16.
__device__ __forceinline__ bool detect_bf16(const ushort* __restrict__ probe) {
    const int lane = threadIdx.x & 63;
    ushort u = probe[(lane & 31) * 2];
    int e = (u >> 7) & 0xFF;
    bool pl = (e >= 117) && (e <= 131) && (lane < 32);
    return __popcll(__ballot(pl)) >= 16;
}

// ---------------------------------------------------------------------------
// Transpose helper (256 threads).
// ---------------------------------------------------------------------------
__device__ __forceinline__ void do_transpose(const void* __restrict__ in,
                                             ushort* __restrict__ out,
                                             int bx, int by, int in_rs, int out_rs,
                                             bool ib, ushort* tile /*32x33*/) {
    const int tx = threadIdx.x & 31, ty = threadIdx.x >> 5;
    #pragma unroll
    for (int rr = 0; rr < 32; rr += 8) {
        size_t idx = (size_t)(by * 32 + ty + rr) * in_rs + bx * 32 + tx;
        float v = ib ? bf2f(((const ushort*)in)[idx]) : ((const float*)in)[idx];
        tile[(ty + rr) * 33 + tx] = f2bf(scrub(v, 1e8f));
    }
    __syncthreads();
    #pragma unroll
    for (int rr = 0; rr < 32; rr += 8) {
        int r = bx * 32 + ty + rr;
        int c = by * 32 + tx;
        out[(size_t)r * out_rs + c] = tile[tx * 33 + (ty + rr)];
    }
}

// ---------------------------------------------------------------------------
// prep: fused LN1 (blocks 0..8191) + Wq^T (8192..8703) + Wkv^T (8704..8831).
// ---------------------------------------------------------------------------
__global__ __launch_bounds__(256) void prep_kernel(const void* __restrict__ xin,
                                                   const void* __restrict__ gin,
                                                   const void* __restrict__ Wq,
                                                   const void* __restrict__ Wkv,
                                                   ushort* __restrict__ xn,
                                                   ushort* __restrict__ wcatT,
                                                   const ushort* __restrict__ probe) {
    const bool ib = detect_bf16(probe);
    const int id = blockIdx.x;
    __shared__ ushort tile[32 * 33];
    __shared__ float red[8];

    if (id >= 8192) {
        if (id < 8704) {
            int t = id - 8192;                  // Wq[1024][512] -> wcatT[0:512)[1024]
            do_transpose(Wq, wcatT, t & 15, t >> 4, 512, 1024, ib, tile);
        } else {
            int t = id - 8704;                  // Wkv[1024][128] -> wcatT[512:640)[1024]
            do_transpose(Wkv, wcatT + (size_t)512 * 1024, t & 3, t >> 2, 128, 1024, ib, tile);
        }
        return;
    }

    const int row = id;
    const int tid = threadIdx.x;
    float v0, v1, v2, v3, g0, g1, g2, g3;
    if (ib) {
        uint2 u = *(const uint2*)((const ushort*)xin + (size_t)row * 1024 + tid * 4);
        v0 = bf2f((ushort)(u.x & 0xFFFF)); v1 = bf2f((ushort)(u.x >> 16));
        v2 = bf2f((ushort)(u.y & 0xFFFF)); v3 = bf2f((ushort)(u.y >> 16));
        uint2 gu = *(const uint2*)((const ushort*)gin + tid * 4);
        g0 = bf2f((ushort)(gu.x & 0xFFFF)); g1 = bf2f((ushort)(gu.x >> 16));
        g2 = bf2f((ushort)(gu.y & 0xFFFF)); g3 = bf2f((ushort)(gu.y >> 16));
    } else {
        float4 xv = *(const float4*)((const float*)xin + (size_t)row * 1024 + tid * 4);
        v0 = xv.x; v1 = xv.y; v2 = xv.z; v3 = xv.w;
        float4 gv = *(const float4*)((const float*)gin + tid * 4);
        g0 = gv.x; g1 = gv.y; g2 = gv.z; g3 = gv.w;
    }
    v0 = scrub(v0, 1e8f); v1 = scrub(v1, 1e8f); v2 = scrub(v2, 1e8f); v3 = scrub(v3, 1e8f);
    g0 = scrub(g0, 1e8f); g1 = scrub(g1, 1e8f); g2 = scrub(g2, 1e8f); g3 = scrub(g3, 1e8f);

    float s  = v0 + v1 + v2 + v3;
    float sq = v0 * v0 + v1 * v1 + v2 * v2 + v3 * v3;
    #pragma unroll
    for (int off = 1; off < 64; off <<= 1) {
        s  += __shfl_xor(s, off);
        sq += __shfl_xor(sq, off);
    }
    const int w = tid >> 6, lane = tid & 63;
    if (lane == 0) { red[w] = s; red[w + 4] = sq; }
    __syncthreads();
    float S  = red[0] + red[1] + red[2] + red[3];
    float SQ = red[4] + red[5] + red[6] + red[7];

    float mean = S * (1.0f / 1024.0f);
    float var  = SQ * (1.0f / 1024.0f) - mean * mean;
    float rstd = rsqrtf(fmaxf(var, 0.0f) + 1e-5f);

    uint2 ov;
    ov.x = pk2((v0 - mean) * rstd * g0, (v1 - mean) * rstd * g1);
    ov.y = pk2((v2 - mean) * rstd * g2, (v3 - mean) * rstd * g3);
    *(uint2*)(xn + (size_t)row * 1024 + tid * 4) = ov;
}

// ---------------------------------------------------------------------------
// Standalone Wout transpose (r6-proven position: after gemm_qkv, xn dead).
// ---------------------------------------------------------------------------
__global__ __launch_bounds__(256) void wout_tr_kernel(const void* __restrict__ Wout,
                                                      ushort* __restrict__ woT,
                                                      const ushort* __restrict__ probe) {
    const bool ib = detect_bf16(probe);
    __shared__ ushort tile[32 * 33];
    do_transpose(Wout, woT, blockIdx.x, blockIdx.y, 1024, 512, ib, tile);
}

// ---------------------------------------------------------------------------
// LN2: input bf16, gamma + OUTPUT dtype detected.
// ---------------------------------------------------------------------------
__global__ __launch_bounds__(256) void ln2_kernel(const ushort* __restrict__ y,
                                                  const void* __restrict__ gin,
                                                  void* __restrict__ out,
                                                  const ushort* __restrict__ probe) {
    const bool ob = detect_bf16(probe);
    const int row = blockIdx.x;
    const int tid = threadIdx.x;

    uint2 u = *(const uint2*)(y + (size_t)row * 1024 + tid * 4);
    float v0 = scrub(bf2f((ushort)(u.x & 0xFFFF)), 1e8f);
    float v1 = scrub(bf2f((ushort)(u.x >> 16)),    1e8f);
    float v2 = scrub(bf2f((ushort)(u.y & 0xFFFF)), 1e8f);
    float v3 = scrub(bf2f((ushort)(u.y >> 16)),    1e8f);

    float g0, g1, g2, g3;
    if (ob) {
        uint2 gu = *(const uint2*)((const ushort*)gin + tid * 4);
        g0 = bf2f((ushort)(gu.x & 0xFFFF)); g1 = bf2f((ushort)(gu.x >> 16));
        g2 = bf2f((ushort)(gu.y & 0xFFFF)); g3 = bf2f((ushort)(gu.y >> 16));
    } else {
        float4 gv = *(const float4*)((const float*)gin + tid * 4);
        g0 = gv.x; g1 = gv.y; g2 = gv.z; g3 = gv.w;
    }
    g0 = scrub(g0, 1e8f); g1 = scrub(g1, 1e8f); g2 = scrub(g2, 1e8f); g3 = scrub(g3, 1e8f);

    float s  = v0 + v1 + v2 + v3;
    float sq = v0 * v0 + v1 * v1 + v2 * v2 + v3 * v3;
    #pragma unroll
    for (int off = 1; off < 64; off <<= 1) {
        s  += __shfl_xor(s, off);
        sq += __shfl_xor(sq, off);
    }
    __shared__ float red[8];
    const int w = tid >> 6, lane = tid & 63;
    if (lane == 0) { red[w] = s; red[w + 4] = sq; }
    __syncthreads();
    float S  = red[0] + red[1] + red[2] + red[3];
    float SQ = red[4] + red[5] + red[6] + red[7];

    float mean = S * (1.0f / 1024.0f);
    float var  = SQ * (1.0f / 1024.0f) - mean * mean;
    float rstd = rsqrtf(fmaxf(var, 0.0f) + 1e-5f);

    float o0 = (v0 - mean) * rstd * g0;
    float o1 = (v1 - mean) * rstd * g1;
    float o2 = (v2 - mean) * rstd * g2;
    float o3 = (v3 - mean) * rstd * g3;
    if (ob) {
        uint2 ov;
        ov.x = pk2(o0, o1);
        ov.y = pk2(o2, o3);
        *(uint2*)((ushort*)out + (size_t)row * 1024 + tid * 4) = ov;
    } else {
        *(float4*)((float*)out + (size_t)row * 1024 + tid * 4) = make_float4(o0, o1, o2, o3);
    }
}

// ---------------------------------------------------------------------------
// Fused QKV GEMM with global_load_lds staging.
// grid (10,128): bx<8 q (l2norm, pre-scaled by log2(e) for exp2 softmax),
// bx==8 k (l2norm), bx==9 v (-> V^T).
// ---------------------------------------------------------------------------
__global__ __launch_bounds__(256) void gemm_qkv(const ushort* __restrict__ A,
                                                const ushort* __restrict__ Bt,
                                                ushort* __restrict__ qb,
                                                ushort* __restrict__ kb,
                                                ushort* __restrict__ vt) {
    __shared__ ushort a_t[64 * 32];
    __shared__ ushort b_t[64 * 32];

    const int bx = blockIdx.x;
    const int n0 = bx * 64, m0 = blockIdx.y * 64;
    const int tid = threadIdx.x;
    const int w = tid >> 6, lane = tid & 63;
    const int fm = lane & 15, quad = lane >> 4;
    const int K = 1024;

    // glds chunk map: thread t -> row t>>2 (0..63), k-octet t&3
    const ushort* ag = A + (size_t)(m0 + (tid >> 2)) * K + (tid & 3) * 8;
    const ushort* bg = Bt + (size_t)(n0 + (tid >> 2)) * K + (tid & 3) * 8;
    ushort* la = a_t + w * 512;   // wave-uniform LDS base
    ushort* lb = b_t + w * 512;

    floatx4 acc[4];
    floatx4 zero4 = {0.0f, 0.0f, 0.0f, 0.0f};
    #pragma unroll
    for (int nt = 0; nt < 4; nt++) acc[nt] = zero4;

    union U8 { uint4 u4; short8 s8; };

    for (int k0 = 0; k0 < K; k0 += 32) {
        __syncthreads();                   // prior iter's frag reads done
        glds16(ag + k0, la);
        glds16(bg + k0, lb);
        __syncthreads();                   // vmcnt drained before reads

        U8 af;
        af.u4 = *(const uint4*)&a_t[(w * 16 + fm) * 32 + quad * 8];
        #pragma unroll
        for (int nt = 0; nt < 4; nt++) {
            U8 bf;
            bf.u4 = *(const uint4*)&b_t[(nt * 16 + fm) * 32 + quad * 8];
            acc[nt] = __builtin_amdgcn_mfma_f32_16x16x32_bf16(af.s8, bf.s8, acc[nt], 0, 0, 0);
        }
    }

    if (bx < 9) {
        // q gets 4*log2(e) so attn's QK accumulates S*log2e -> bare exp2.
        const float qsc = (bx < 8) ? 5.7707801636f : 4.0f;
        float sc[4];
        #pragma unroll
        for (int r = 0; r < 4; r++) {
            float ss = acc[0][r] * acc[0][r] + acc[1][r] * acc[1][r]
                     + acc[2][r] * acc[2][r] + acc[3][r] * acc[3][r];
            ss += __shfl_xor(ss, 1);
            ss += __shfl_xor(ss, 2);
            ss += __shfl_xor(ss, 4);
            ss += __shfl_xor(ss, 8);
            sc[r] = qsc / fmaxf(sqrtf(ss), 1e-12f);
        }
        ushort* op;
        int rs;
        if (bx < 8) { op = qb + n0; rs = 512; }
        else        { op = kb;      rs = 64;  }
        #pragma unroll
        for (int nt = 0; nt < 4; nt++)
            #pragma unroll
            for (int r = 0; r < 4; r++)
                op[(size_t)(m0 + w * 16 + quad * 4 + r) * rs + nt * 16 + fm] =
                    f2bf(acc[nt][r] * sc[r]);
    } else {
        const int b = m0 >> 11;
        const int jb = (m0 & 2047) + w * 16 + quad * 4;
        ushort* vb = vt + (size_t)b * 64 * 2048 + jb;
        #pragma unroll
        for (int nt = 0; nt < 4; nt++) {
            uint2 pv;
            pv.x = pk2(acc[nt][0], acc[nt][1]);
            pv.y = pk2(acc[nt][2], acc[nt][3]);
            *(uint2*)(vb + (size_t)(nt * 16 + fm) * 2048) = pv;
        }
    }
}

// ---------------------------------------------------------------------------
// Out-projection GEMM, m97-style: 128x128 tile, BK=32, global_load_lds w=16.
// ---------------------------------------------------------------------------
__global__ __launch_bounds__(256) void gemm_bt128(const ushort* __restrict__ A,
                                                  const ushort* __restrict__ Bt,
                                                  ushort* __restrict__ C,
                                                  int M, int N, int K) {
    __shared__ ushort a_t[128][32];
    __shared__ ushort b_t[128][32];

    const int n0 = blockIdx.x * 128, m0 = blockIdx.y * 128;
    const int tid = threadIdx.x;
    const int w = tid >> 6, lane = tid & 63;
    const int fm = lane & 15, quad = lane >> 4;

    const int c0 = tid, c1 = tid + 256;
    const ushort* ag0 = A + (size_t)(m0 + (c0 >> 2)) * K + (c0 & 3) * 8;
    const ushort* ag1 = A + (size_t)(m0 + (c1 >> 2)) * K + (c1 & 3) * 8;
    const ushort* bg0 = Bt + (size_t)(n0 + (c0 >> 2)) * K + (c0 & 3) * 8;
    const ushort* bg1 = Bt + (size_t)(n0 + (c1 >> 2)) * K + (c1 & 3) * 8;
    ushort* la0 = &a_t[0][0] + w * 512;
    ushort* la1 = &a_t[0][0] + 2048 + w * 512;
    ushort* lb0 = &b_t[0][0] + w * 512;
    ushort* lb1 = &b_t[0][0] + 2048 + w * 512;

    floatx4 acc[2][8];
    floatx4 zero4 = {0.0f, 0.0f, 0.0f, 0.0f};
    #pragma unroll
    for (int mt = 0; mt < 2; mt++)
        #pragma unroll
        for (int nt = 0; nt < 8; nt++) acc[mt][nt] = zero4;

    union U8 { uint4 u4; short8 s8; };

    for (int k0 = 0; k0 < K; k0 += 32) {
        __syncthreads();
        glds16(ag0 + k0, la0);
        glds16(ag1 + k0, la1);
        glds16(bg0 + k0, lb0);
        glds16(bg1 + k0, lb1);
        __syncthreads();

        U8 af[2];
        #pragma unroll
        for (int mt = 0; mt < 2; mt++)
            af[mt].u4 = *(const uint4*)&a_t[w * 32 + mt * 16 + fm][quad * 8];
        #pragma unroll
        for (int nt = 0; nt < 8; nt++) {
            U8 bf;
            bf.u4 = *(const uint4*)&b_t[nt * 16 + fm][quad * 8];
            acc[0][nt] = __builtin_amdgcn_mfma_f32_16x16x32_bf16(af[0].s8, bf.s8, acc[0][nt], 0, 0, 0);
            acc[1][nt] = __builtin_amdgcn_mfma_f32_16x16x32_bf16(af[1].s8, bf.s8, acc[1][nt], 0, 0, 0);
        }
    }

    #pragma unroll
    for (int mt = 0; mt < 2; mt++)
        #pragma unroll
        for (int nt = 0; nt < 8; nt++)
            #pragma unroll
            for (int r = 0; r < 4; r++)
                C[(size_t)(m0 + w * 32 + mt * 16 + quad * 4 + r) * N + n0 + nt * 16 + fm] =
                    f2bf(acc[mt][nt][r]);
}

// ---------------------------------------------------------------------------
// Flash attention, 32x32x16 MFMA + split-K restructure.
//
// Why: r1 counters showed attn LDS-read-bound (16 waves x 32 rounds x 16
// ds_read_b128 ~ 98k cyc/CU ~ 68% of runtime; MfmaUtil 21%, VALU 46%).
// 32x32x16 consumes the same one-b128 fragment per MFMA but does 2x FLOPs
// -> per-FLOP LDS reads halve; matrix-pipe time drops 17% (8.07 cyc vs
// 2x4.85). Each wave now owns 32 queries; to keep 16 waves/CU the 8 waves
// split keys: w>>2==0 -> keys [0,1024), ==1 -> [1024,2048). Partials (O^T
// 32 f32/lane + lsum) combined once via LDS at the end (no running max in
// this softmax -> split-K is a plain sum).
//
// In-register P: K tile rows permuted so LDS position p holds global key
// bitswap_2,3(p). Then QK^T's C regs are exactly the PV B-frags in reg
// order: key(reg,hi) = (reg&3) + 4*((reg>>2)&1) + 8*hi + 16*(reg>>3) + 32*kt
// = linear B index. V stays natural-col. exp2 path: Q pre-scaled by log2e
// (gemm_qkv) + C init = -16*log2e -> softmax is a bare v_exp_f32.
//
// XOR swizzle (octet ^ (row&7)) on K/V staging + frag reads: conflict-free.
// LDS: 2 buf x 2 half x (8K K + 8K V) = 64 KB -> 2 blocks/CU.
// ---------------------------------------------------------------------------
__global__ __launch_bounds__(512, 4) void attn_kernel(const ushort* __restrict__ q,
                                                      const ushort* __restrict__ kb,
                                                      const ushort* __restrict__ vt,
                                                      ushort* __restrict__ out) {
    __shared__ ushort k_t[2][2][64 * 64];   // [buf][half][pos][d], permuted+swizzled
    __shared__ ushort v_t[2][2][64 * 64];   // [buf][half][d][key], swizzled

    const int i0 = blockIdx.x * 128;
    const int h0 = blockIdx.y, b = blockIdx.z;
    const int tid = threadIdx.x, w = tid >> 6, lane = tid & 63;
    const int qg = w & 3;          // query group (32 queries)
    const int kh = w >> 2;         // key half: 0 -> [0,1024), 1 -> [1024,2048)
    const int cq = lane & 31;      // C col = query, frag row = cq
    const int hi = lane >> 5;      // k-half within fragment
    const int sw = cq & 7;

    union U8 { uint4 u4; short8 s8; };

    // Q B-frags: qf[dm] holds Q[q=cq][d = 16*dm + 8*hi + j]
    const ushort* qbase = q + (size_t)(b * 2048 + i0 + qg * 32 + cq) * 512 + h0 * 64 + hi * 8;
    U8 qf[4];
    #pragma unroll
    for (int dm = 0; dm < 4; dm++) qf[dm].u4 = *(const uint4*)(qbase + dm * 16);

    floatx16 acc0, acc1;           // O^T tiles: d 0..31 (acc0), 32..63 (acc1)
    #pragma unroll
    for (int i = 0; i < 16; i++) { acc0[i] = 0.0f; acc1[i] = 0.0f; }
    float lsum = 0.0f;

    const ushort* kbb = kb + (size_t)b * 2048 * 64;
    const ushort* vtb = vt + (size_t)b * 64 * 2048;

    // staging: wave w covers LDS rows w*8..w*8+7 of each tile; lane i -> row
    // w*8+(i>>3), global octet (i&7)^(row&7). K source row = bitswap_2,3(srow).
    const int srow = w * 8 + (lane >> 3);
    const int soct = (lane & 7) ^ (srow & 7);
    const int prow = (srow & ~12) | ((srow & 4) << 1) | ((srow & 8) >> 1);
    const ushort* kgl = kbb + (size_t)prow * 64 + soct * 8;
    const ushort* vgl = vtb + (size_t)srow * 2048 + soct * 8;
    ushort* kldb = &k_t[0][0][0] + w * 512;   // wave-uniform dest bases
    ushort* vldb = &v_t[0][0][0] + w * 512;

    // per-lane swizzled octet offsets (elems), shared by K(dm) and V(m) reads
    int koff[4];
    #pragma unroll
    for (int i = 0; i < 4; i++) koff[i] = ((2 * i + hi) ^ sw) * 8;
    const int rb0 = cq * 64, rb1 = rb0 + 2048;   // frag row bases (tile 0/1)

    auto compute = [&](const ushort* ktile, const ushort* vtile) {
        U8 pb0, pb1, pb2, pb3;
        // --- C-tile 0 (positions 0..31): QK^T, exp2, pack ---
        {
            floatx16 st;
            #pragma unroll
            for (int i = 0; i < 16; i++) st[i] = -23.0831206f;   // -16*log2(e)
            #pragma unroll
            for (int dm = 0; dm < 4; dm++) {
                U8 kf;
                kf.u4 = *(const uint4*)&ktile[rb0 + koff[dm]];
                st = __builtin_amdgcn_mfma_f32_32x32x16_bf16(kf.s8, qf[dm].s8, st, 0, 0, 0);
            }
            float p_[16];
            #pragma unroll
            for (int r = 0; r < 16; r++) p_[r] = exp2f(st[r]);
            lsum += (((p_[0] + p_[1]) + (p_[2] + p_[3])) + ((p_[4] + p_[5]) + (p_[6] + p_[7])))
                  + (((p_[8] + p_[9]) + (p_[10] + p_[11])) + ((p_[12] + p_[13]) + (p_[14] + p_[15])));
            pb0.u4.x = pk2(p_[0], p_[1]);   pb0.u4.y = pk2(p_[2], p_[3]);
            pb0.u4.z = pk2(p_[4], p_[5]);   pb0.u4.w = pk2(p_[6], p_[7]);
            pb1.u4.x = pk2(p_[8], p_[9]);   pb1.u4.y = pk2(p_[10], p_[11]);
            pb1.u4.z = pk2(p_[12], p_[13]); pb1.u4.w = pk2(p_[14], p_[15]);
        }
        // --- C-tile 1 (positions 32..63) ---
        {
            floatx16 st;
            #pragma unroll
            for (int i = 0; i < 16; i++) st[i] = -23.0831206f;
            #pragma unroll
            for (int dm = 0; dm < 4; dm++) {
                U8 kf;
                kf.u4 = *(const uint4*)&ktile[rb1 + koff[dm]];
                st = __builtin_amdgcn_mfma_f32_32x32x16_bf16(kf.s8, qf[dm].s8, st, 0, 0, 0);
            }
            float p_[16];
            #pragma unroll
            for (int r = 0; r < 16; r++) p_[r] = exp2f(st[r]);
            lsum += (((p_[0] + p_[1]) + (p_[2] + p_[3])) + ((p_[4] + p_[5]) + (p_[6] + p_[7])))
                  + (((p_[8] + p_[9]) + (p_[10] + p_[11])) + ((p_[12] + p_[13]) + (p_[14] + p_[15])));
            pb2.u4.x = pk2(p_[0], p_[1]);   pb2.u4.y = pk2(p_[2], p_[3]);
            pb2.u4.z = pk2(p_[4], p_[5]);   pb2.u4.w = pk2(p_[6], p_[7]);
            pb3.u4.x = pk2(p_[8], p_[9]);   pb3.u4.y = pk2(p_[10], p_[11]);
            pb3.u4.z = pk2(p_[12], p_[13]); pb3.u4.w = pk2(p_[14], p_[15]);
        }
        // --- PV: O^T(d-tile) += V^T(k-slice) x P^T ---
        U8 vf;
        vf.u4 = *(const uint4*)&vtile[rb0 + koff[0]];
        acc0 = __builtin_amdgcn_mfma_f32_32x32x16_bf16(vf.s8, pb0.s8, acc0, 0, 0, 0);
        vf.u4 = *(const uint4*)&vtile[rb0 + koff[1]];
        acc0 = __builtin_amdgcn_mfma_f32_32x32x16_bf16(vf.s8, pb1.s8, acc0, 0, 0, 0);
        vf.u4 = *(const uint4*)&vtile[rb0 + koff[2]];
        acc0 = __builtin_amdgcn_mfma_f32_32x32x16_bf16(vf.s8, pb2.s8, acc0, 0, 0, 0);
        vf.u4 = *(const uint4*)&vtile[rb0 + koff[3]];
        acc0 = __builtin_amdgcn_mfma_f32_32x32x16_bf16(vf.s8, pb3.s8, acc0, 0, 0, 0);
        vf.u4 = *(const uint4*)&vtile[rb1 + koff[0]];
        acc1 = __builtin_amdgcn_mfma_f32_32x32x16_bf16(vf.s8, pb0.s8, acc1, 0, 0, 0);
        vf.u4 = *(const uint4*)&vtile[rb1 + koff[1]];
        acc1 = __builtin_amdgcn_mfma_f32_32x32x16_bf16(vf.s8, pb1.s8, acc1, 0, 0, 0);
        vf.u4 = *(const uint4*)&vtile[rb1 + koff[2]];
        acc1 = __builtin_amdgcn_mfma_f32_32x32x16_bf16(vf.s8, pb2.s8, acc1, 0, 0, 0);
        vf.u4 = *(const uint4*)&vtile[rb1 + koff[3]];
        acc1 = __builtin_amdgcn_mfma_f32_32x32x16_bf16(vf.s8, pb3.s8, acc1, 0, 0, 0);
    };

    // prologue: stage step 0 (both halves) into buf0
    glds16(kgl, kldb);
    glds16(kgl + (size_t)1024 * 64, kldb + 4096);
    glds16(vgl, vldb);
    glds16(vgl + 1024, vldb + 4096);
    __syncthreads();

    const ushort* mk = &k_t[0][0][0] + kh * 4096;
    const ushort* mv = &v_t[0][0][0] + kh * 4096;

    for (int s = 0; s < 16; s++) {
        const int cur = (s & 1) << 13;        // buf elem offset: 0 / 8192
        const int nxt = cur ^ 8192;
        if (s < 15) {
            const int j = (s + 1) * 64;
            glds16(kgl + (size_t)j * 64, kldb + nxt);
            glds16(kgl + (size_t)(1024 + j) * 64, kldb + nxt + 4096);
            glds16(vgl + j, vldb + nxt);
            glds16(vgl + 1024 + j, vldb + nxt + 4096);
        }
        compute(mk + cur, mv + cur);
        __syncthreads();                      // drains nxt staging; WAR on cur
    }

    // ---- split-K combine via LDS (stride-18 f32 to dodge bank conflicts) ----
    float* xa = (float*)&k_t[0][0][0];        // acc0 + lsum, 256*18*4 = 18.4 KB
    float* xb = (float*)&v_t[0][0][0];        // acc1
    if (kh == 1) {
        float* da = xa + (qg * 64 + lane) * 18;
        float* db = xb + (qg * 64 + lane) * 18;
        #pragma unroll
        for (int i = 0; i < 16; i++) { da[i] = acc0[i]; db[i] = acc1[i]; }
        da[16] = lsum;
    }
    __syncthreads();
    if (kh == 1) return;
    {
        const float* sa = xa + (qg * 64 + lane) * 18;
        const float* sb = xb + (qg * 64 + lane) * 18;
        #pragma unroll
        for (int i = 0; i < 16; i++) { acc0[i] += sa[i]; acc1[i] += sb[i]; }
        lsum += sa[16];
    }
    lsum += __shfl_xor(lsum, 32);             // combine hi/lo key-lane halves
    float li = 1.0f / fmaxf(lsum, 1e-30f);

    // write out: d = dt*32 + 8*t + 4*hi + s for reg 4t+s
    ushort* ob = out + (size_t)(b * 2048 + i0 + qg * 32 + cq) * 512 + h0 * 64 + hi * 4;
    #pragma unroll
    for (int t = 0; t < 4; t++) {
        uint2 ov;
        ov.x = pk2(acc0[4 * t] * li, acc0[4 * t + 1] * li);
        ov.y = pk2(acc0[4 * t + 2] * li, acc0[4 * t + 3] * li);
        *(uint2*)(ob + t * 8) = ov;
        ov.x = pk2(acc1[4 * t] * li, acc1[4 * t + 1] * li);
        ov.y = pk2(acc1[4 * t + 2] * li, acc1[4 * t + 3] * li);
        *(uint2*)(ob + 32 + t * 8) = ov;
    }
}

// ---------------------------------------------------------------------------
// Memory plan (bf16 intermediates, ws_size needed = 16MB):
//   d_out: xn [0:16MB) (dead after gemm_qkv) -> ao [0:8MB), woT [8:16MB)
//   ws:    qb [0:8), kb [8:9), vt [9:11), wcatT [11:12.25); y [0:16) after attn.
// Dispatches (6): prep, gemm_qkv, wout_tr, attn, gemm_bt128, ln2.
// ---------------------------------------------------------------------------
extern "C" void kernel_launch(void* const* d_in, const int* in_sizes, int n_in,
                              void* d_out, int out_size, void* d_ws, size_t ws_size,
                              hipStream_t stream) {
    const void* x          = d_in[0];
    const void* norm_g     = d_in[1];
    const void* Wq         = d_in[2];
    const void* Wkv        = d_in[3];
    const void* Wout       = d_in[4];
    const void* out_norm_g = d_in[5];
    const ushort* probe = (const ushort*)d_in[0];
    ushort* ws = (ushort*)d_ws;

    const size_t M1 = 1024 * 1024 / 2;  // bf16 elems per MB
    ushort* xn    = (ushort*)d_out;
    ushort* ao    = (ushort*)d_out;
    ushort* woT   = (ushort*)((char*)d_out + (8u << 20));
    ushort* qb    = ws;
    ushort* kb    = ws + 8 * M1;
    ushort* vt    = ws + 9 * M1;
    ushort* wcatT = ws + 11 * M1;
    ushort* y     = ws;

    // prep: LN1 + Wq^T + Wkv^T fused
    prep_kernel<<<8832, 256, 0, stream>>>(x, norm_g, Wq, Wkv, xn, wcatT, probe);

    // fused q/k/v projection + l2norm + V^T
    gemm_qkv<<<dim3(10, 128), 256, 0, stream>>>(xn, wcatT, qb, kb, vt);

    // Wout^T -> d_out[8:16MB) (xn dead now)
    wout_tr_kernel<<<dim3(32, 16), 256, 0, stream>>>(Wout, woT, probe);

    // attention -> ao
    attn_kernel<<<dim3(16, 8, 4), 512, 0, stream>>>(qb, kb, vt, ao);

    // y = ao @ Wout  (128-tile, global_load_lds)
    gemm_bt128<<<dim3(8, 64), 256, 0, stream>>>(ao, woT, y, 8192, 1024, 512);

    // LN2: y -> final output
    ln2_kernel<<<8192, 256, 0, stream>>>(y, out_norm_g, d_out, probe);
}

// Round 3
// 214.116 us; speedup vs baseline: 1.1590x; 1.1590x over previous
//
#include <hip/hip_runtime.h>
#include <hip/hip_bf16.h>

typedef __attribute__((ext_vector_type(8))) short short8;
typedef __attribute__((ext_vector_type(4))) float floatx4;
typedef __attribute__((ext_vector_type(16))) float floatx16;

__device__ __forceinline__ float bf2f(ushort u) {
    return __uint_as_float(((unsigned int)u) << 16);
}
__device__ __forceinline__ ushort f2bf(float f) {
    unsigned int u = __float_as_uint(f);
    unsigned int r = (u + 0x7FFFu + ((u >> 16) & 1u)) >> 16;
    return (ushort)r;
}
// packed f32x2 -> bf16x2
__device__ __forceinline__ unsigned int pk2(float a, float b) {
    union { __hip_bfloat162 h; unsigned int u; } cv;
    cv.h = __float22bfloat162_rn(make_float2(a, b));
    return cv.u;
}
__device__ __forceinline__ float scrub(float v, float lim) {
    return fminf(fmaxf(v, -lim), lim);
}
// async global->LDS, 16B per lane (lane i lands at wave-uniform lds base + 16*i)
__device__ __forceinline__ void glds16(const ushort* g, ushort* l) {
    __builtin_amdgcn_global_load_lds((const __attribute__((address_space(1))) void*)g,
                                     (__attribute__((address_space(3))) void*)l, 16, 0, 0);
}

// Wave-uniform dtype probe on x: bf16 N(0,1) data has exponent byte in [117,131]
// ~99% at even ushort indices; fp32-as-ushort gives ~6%. 32 samples, thr 16.
__device__ __forceinline__ bool detect_bf16(const ushort* __restrict__ probe) {
    const int lane = threadIdx.x & 63;
    ushort u = probe[(lane & 31) * 2];
    int e = (u >> 7) & 0xFF;
    bool pl = (e >= 117) && (e <= 131) && (lane < 32);
    return __popcll(__ballot(pl)) >= 16;
}

// ---------------------------------------------------------------------------
// Transpose helper (256 threads).
// ---------------------------------------------------------------------------
__device__ __forceinline__ void do_transpose(const void* __restrict__ in,
                                             ushort* __restrict__ out,
                                             int bx, int by, int in_rs, int out_rs,
                                             bool ib, ushort* tile /*32x33*/) {
    const int tx = threadIdx.x & 31, ty = threadIdx.x >> 5;
    #pragma unroll
    for (int rr = 0; rr < 32; rr += 8) {
        size_t idx = (size_t)(by * 32 + ty + rr) * in_rs + bx * 32 + tx;
        float v = ib ? bf2f(((const ushort*)in)[idx]) : ((const float*)in)[idx];
        tile[(ty + rr) * 33 + tx] = f2bf(scrub(v, 1e8f));
    }
    __syncthreads();
    #pragma unroll
    for (int rr = 0; rr < 32; rr += 8) {
        int r = bx * 32 + ty + rr;
        int c = by * 32 + tx;
        out[(size_t)r * out_rs + c] = tile[tx * 33 + (ty + rr)];
    }
}

// ---------------------------------------------------------------------------
// prep: fused LN1 (blocks 0..8191) + Wq^T (8192..8703) + Wkv^T (8704..8831).
// ---------------------------------------------------------------------------
__global__ __launch_bounds__(256) void prep_kernel(const void* __restrict__ xin,
                                                   const void* __restrict__ gin,
                                                   const void* __restrict__ Wq,
                                                   const void* __restrict__ Wkv,
                                                   ushort* __restrict__ xn,
                                                   ushort* __restrict__ wcatT,
                                                   const ushort* __restrict__ probe) {
    const bool ib = detect_bf16(probe);
    const int id = blockIdx.x;
    __shared__ ushort tile[32 * 33];
    __shared__ float red[8];

    if (id >= 8192) {
        if (id < 8704) {
            int t = id - 8192;                  // Wq[1024][512] -> wcatT[0:512)[1024]
            do_transpose(Wq, wcatT, t & 15, t >> 4, 512, 1024, ib, tile);
        } else {
            int t = id - 8704;                  // Wkv[1024][128] -> wcatT[512:640)[1024]
            do_transpose(Wkv, wcatT + (size_t)512 * 1024, t & 3, t >> 2, 128, 1024, ib, tile);
        }
        return;
    }

    const int row = id;
    const int tid = threadIdx.x;
    float v0, v1, v2, v3, g0, g1, g2, g3;
    if (ib) {
        uint2 u = *(const uint2*)((const ushort*)xin + (size_t)row * 1024 + tid * 4);
        v0 = bf2f((ushort)(u.x & 0xFFFF)); v1 = bf2f((ushort)(u.x >> 16));
        v2 = bf2f((ushort)(u.y & 0xFFFF)); v3 = bf2f((ushort)(u.y >> 16));
        uint2 gu = *(const uint2*)((const ushort*)gin + tid * 4);
        g0 = bf2f((ushort)(gu.x & 0xFFFF)); g1 = bf2f((ushort)(gu.x >> 16));
        g2 = bf2f((ushort)(gu.y & 0xFFFF)); g3 = bf2f((ushort)(gu.y >> 16));
    } else {
        float4 xv = *(const float4*)((const float*)xin + (size_t)row * 1024 + tid * 4);
        v0 = xv.x; v1 = xv.y; v2 = xv.z; v3 = xv.w;
        float4 gv = *(const float4*)((const float*)gin + tid * 4);
        g0 = gv.x; g1 = gv.y; g2 = gv.z; g3 = gv.w;
    }
    v0 = scrub(v0, 1e8f); v1 = scrub(v1, 1e8f); v2 = scrub(v2, 1e8f); v3 = scrub(v3, 1e8f);
    g0 = scrub(g0, 1e8f); g1 = scrub(g1, 1e8f); g2 = scrub(g2, 1e8f); g3 = scrub(g3, 1e8f);

    float s  = v0 + v1 + v2 + v3;
    float sq = v0 * v0 + v1 * v1 + v2 * v2 + v3 * v3;
    #pragma unroll
    for (int off = 1; off < 64; off <<= 1) {
        s  += __shfl_xor(s, off);
        sq += __shfl_xor(sq, off);
    }
    const int w = tid >> 6, lane = tid & 63;
    if (lane == 0) { red[w] = s; red[w + 4] = sq; }
    __syncthreads();
    float S  = red[0] + red[1] + red[2] + red[3];
    float SQ = red[4] + red[5] + red[6] + red[7];

    float mean = S * (1.0f / 1024.0f);
    float var  = SQ * (1.0f / 1024.0f) - mean * mean;
    float rstd = rsqrtf(fmaxf(var, 0.0f) + 1e-5f);

    uint2 ov;
    ov.x = pk2((v0 - mean) * rstd * g0, (v1 - mean) * rstd * g1);
    ov.y = pk2((v2 - mean) * rstd * g2, (v3 - mean) * rstd * g3);
    *(uint2*)(xn + (size_t)row * 1024 + tid * 4) = ov;
}

// ---------------------------------------------------------------------------
// Standalone Wout transpose (r6-proven position: after gemm_qkv, xn dead).
// ---------------------------------------------------------------------------
__global__ __launch_bounds__(256) void wout_tr_kernel(const void* __restrict__ Wout,
                                                      ushort* __restrict__ woT,
                                                      const ushort* __restrict__ probe) {
    const bool ib = detect_bf16(probe);
    __shared__ ushort tile[32 * 33];
    do_transpose(Wout, woT, blockIdx.x, blockIdx.y, 1024, 512, ib, tile);
}

// ---------------------------------------------------------------------------
// LN2: input bf16, gamma + OUTPUT dtype detected.
// ---------------------------------------------------------------------------
__global__ __launch_bounds__(256) void ln2_kernel(const ushort* __restrict__ y,
                                                  const void* __restrict__ gin,
                                                  void* __restrict__ out,
                                                  const ushort* __restrict__ probe) {
    const bool ob = detect_bf16(probe);
    const int row = blockIdx.x;
    const int tid = threadIdx.x;

    uint2 u = *(const uint2*)(y + (size_t)row * 1024 + tid * 4);
    float v0 = scrub(bf2f((ushort)(u.x & 0xFFFF)), 1e8f);
    float v1 = scrub(bf2f((ushort)(u.x >> 16)),    1e8f);
    float v2 = scrub(bf2f((ushort)(u.y & 0xFFFF)), 1e8f);
    float v3 = scrub(bf2f((ushort)(u.y >> 16)),    1e8f);

    float g0, g1, g2, g3;
    if (ob) {
        uint2 gu = *(const uint2*)((const ushort*)gin + tid * 4);
        g0 = bf2f((ushort)(gu.x & 0xFFFF)); g1 = bf2f((ushort)(gu.x >> 16));
        g2 = bf2f((ushort)(gu.y & 0xFFFF)); g3 = bf2f((ushort)(gu.y >> 16));
    } else {
        float4 gv = *(const float4*)((const float*)gin + tid * 4);
        g0 = gv.x; g1 = gv.y; g2 = gv.z; g3 = gv.w;
    }
    g0 = scrub(g0, 1e8f); g1 = scrub(g1, 1e8f); g2 = scrub(g2, 1e8f); g3 = scrub(g3, 1e8f);

    float s  = v0 + v1 + v2 + v3;
    float sq = v0 * v0 + v1 * v1 + v2 * v2 + v3 * v3;
    #pragma unroll
    for (int off = 1; off < 64; off <<= 1) {
        s  += __shfl_xor(s, off);
        sq += __shfl_xor(sq, off);
    }
    __shared__ float red[8];
    const int w = tid >> 6, lane = tid & 63;
    if (lane == 0) { red[w] = s; red[w + 4] = sq; }
    __syncthreads();
    float S  = red[0] + red[1] + red[2] + red[3];
    float SQ = red[4] + red[5] + red[6] + red[7];

    float mean = S * (1.0f / 1024.0f);
    float var  = SQ * (1.0f / 1024.0f) - mean * mean;
    float rstd = rsqrtf(fmaxf(var, 0.0f) + 1e-5f);

    float o0 = (v0 - mean) * rstd * g0;
    float o1 = (v1 - mean) * rstd * g1;
    float o2 = (v2 - mean) * rstd * g2;
    float o3 = (v3 - mean) * rstd * g3;
    if (ob) {
        uint2 ov;
        ov.x = pk2(o0, o1);
        ov.y = pk2(o2, o3);
        *(uint2*)((ushort*)out + (size_t)row * 1024 + tid * 4) = ov;
    } else {
        *(float4*)((float*)out + (size_t)row * 1024 + tid * 4) = make_float4(o0, o1, o2, o3);
    }
}

// ---------------------------------------------------------------------------
// Fused QKV GEMM with global_load_lds staging.
// grid (10,128): bx<8 q (l2norm, pre-scaled by log2(e) for exp2 softmax),
// bx==8 k (l2norm), bx==9 v (-> V^T).
// ---------------------------------------------------------------------------
__global__ __launch_bounds__(256) void gemm_qkv(const ushort* __restrict__ A,
                                                const ushort* __restrict__ Bt,
                                                ushort* __restrict__ qb,
                                                ushort* __restrict__ kb,
                                                ushort* __restrict__ vt) {
    __shared__ ushort a_t[64 * 32];
    __shared__ ushort b_t[64 * 32];

    const int bx = blockIdx.x;
    const int n0 = bx * 64, m0 = blockIdx.y * 64;
    const int tid = threadIdx.x;
    const int w = tid >> 6, lane = tid & 63;
    const int fm = lane & 15, quad = lane >> 4;
    const int K = 1024;

    // glds chunk map: thread t -> row t>>2 (0..63), k-octet t&3
    const ushort* ag = A + (size_t)(m0 + (tid >> 2)) * K + (tid & 3) * 8;
    const ushort* bg = Bt + (size_t)(n0 + (tid >> 2)) * K + (tid & 3) * 8;
    ushort* la = a_t + w * 512;   // wave-uniform LDS base
    ushort* lb = b_t + w * 512;

    floatx4 acc[4];
    floatx4 zero4 = {0.0f, 0.0f, 0.0f, 0.0f};
    #pragma unroll
    for (int nt = 0; nt < 4; nt++) acc[nt] = zero4;

    union U8 { uint4 u4; short8 s8; };

    for (int k0 = 0; k0 < K; k0 += 32) {
        __syncthreads();                   // prior iter's frag reads done
        glds16(ag + k0, la);
        glds16(bg + k0, lb);
        __syncthreads();                   // vmcnt drained before reads

        U8 af;
        af.u4 = *(const uint4*)&a_t[(w * 16 + fm) * 32 + quad * 8];
        #pragma unroll
        for (int nt = 0; nt < 4; nt++) {
            U8 bf;
            bf.u4 = *(const uint4*)&b_t[(nt * 16 + fm) * 32 + quad * 8];
            acc[nt] = __builtin_amdgcn_mfma_f32_16x16x32_bf16(af.s8, bf.s8, acc[nt], 0, 0, 0);
        }
    }

    if (bx < 9) {
        // q gets 4*log2(e) so attn's QK accumulates S*log2e -> bare exp2.
        const float qsc = (bx < 8) ? 5.7707801636f : 4.0f;
        float sc[4];
        #pragma unroll
        for (int r = 0; r < 4; r++) {
            float ss = acc[0][r] * acc[0][r] + acc[1][r] * acc[1][r]
                     + acc[2][r] * acc[2][r] + acc[3][r] * acc[3][r];
            ss += __shfl_xor(ss, 1);
            ss += __shfl_xor(ss, 2);
            ss += __shfl_xor(ss, 4);
            ss += __shfl_xor(ss, 8);
            sc[r] = qsc / fmaxf(sqrtf(ss), 1e-12f);
        }
        ushort* op;
        int rs;
        if (bx < 8) { op = qb + n0; rs = 512; }
        else        { op = kb;      rs = 64;  }
        #pragma unroll
        for (int nt = 0; nt < 4; nt++)
            #pragma unroll
            for (int r = 0; r < 4; r++)
                op[(size_t)(m0 + w * 16 + quad * 4 + r) * rs + nt * 16 + fm] =
                    f2bf(acc[nt][r] * sc[r]);
    } else {
        const int b = m0 >> 11;
        const int jb = (m0 & 2047) + w * 16 + quad * 4;
        ushort* vb = vt + (size_t)b * 64 * 2048 + jb;
        #pragma unroll
        for (int nt = 0; nt < 4; nt++) {
            uint2 pv;
            pv.x = pk2(acc[nt][0], acc[nt][1]);
            pv.y = pk2(acc[nt][2], acc[nt][3]);
            *(uint2*)(vb + (size_t)(nt * 16 + fm) * 2048) = pv;
        }
    }
}

// ---------------------------------------------------------------------------
// Out-projection GEMM, m97-style: 128x128 tile, BK=32, global_load_lds w=16.
// ---------------------------------------------------------------------------
__global__ __launch_bounds__(256) void gemm_bt128(const ushort* __restrict__ A,
                                                  const ushort* __restrict__ Bt,
                                                  ushort* __restrict__ C,
                                                  int M, int N, int K) {
    __shared__ ushort a_t[128][32];
    __shared__ ushort b_t[128][32];

    const int n0 = blockIdx.x * 128, m0 = blockIdx.y * 128;
    const int tid = threadIdx.x;
    const int w = tid >> 6, lane = tid & 63;
    const int fm = lane & 15, quad = lane >> 4;

    const int c0 = tid, c1 = tid + 256;
    const ushort* ag0 = A + (size_t)(m0 + (c0 >> 2)) * K + (c0 & 3) * 8;
    const ushort* ag1 = A + (size_t)(m0 + (c1 >> 2)) * K + (c1 & 3) * 8;
    const ushort* bg0 = Bt + (size_t)(n0 + (c0 >> 2)) * K + (c0 & 3) * 8;
    const ushort* bg1 = Bt + (size_t)(n0 + (c1 >> 2)) * K + (c1 & 3) * 8;
    ushort* la0 = &a_t[0][0] + w * 512;
    ushort* la1 = &a_t[0][0] + 2048 + w * 512;
    ushort* lb0 = &b_t[0][0] + w * 512;
    ushort* lb1 = &b_t[0][0] + 2048 + w * 512;

    floatx4 acc[2][8];
    floatx4 zero4 = {0.0f, 0.0f, 0.0f, 0.0f};
    #pragma unroll
    for (int mt = 0; mt < 2; mt++)
        #pragma unroll
        for (int nt = 0; nt < 8; nt++) acc[mt][nt] = zero4;

    union U8 { uint4 u4; short8 s8; };

    for (int k0 = 0; k0 < K; k0 += 32) {
        __syncthreads();
        glds16(ag0 + k0, la0);
        glds16(ag1 + k0, la1);
        glds16(bg0 + k0, lb0);
        glds16(bg1 + k0, lb1);
        __syncthreads();

        U8 af[2];
        #pragma unroll
        for (int mt = 0; mt < 2; mt++)
            af[mt].u4 = *(const uint4*)&a_t[w * 32 + mt * 16 + fm][quad * 8];
        #pragma unroll
        for (int nt = 0; nt < 8; nt++) {
            U8 bf;
            bf.u4 = *(const uint4*)&b_t[nt * 16 + fm][quad * 8];
            acc[0][nt] = __builtin_amdgcn_mfma_f32_16x16x32_bf16(af[0].s8, bf.s8, acc[0][nt], 0, 0, 0);
            acc[1][nt] = __builtin_amdgcn_mfma_f32_16x16x32_bf16(af[1].s8, bf.s8, acc[1][nt], 0, 0, 0);
        }
    }

    #pragma unroll
    for (int mt = 0; mt < 2; mt++)
        #pragma unroll
        for (int nt = 0; nt < 8; nt++)
            #pragma unroll
            for (int r = 0; r < 4; r++)
                C[(size_t)(m0 + w * 32 + mt * 16 + quad * 4 + r) * N + n0 + nt * 16 + fm] =
                    f2bf(acc[mt][nt][r]);
}

// ---------------------------------------------------------------------------
// Flash attention, 32x32x16 MFMA, no split-K (r2 spill fix).
//
// r2 post-mortem: __launch_bounds__(512,4) capped regs at 128 total; compiler
// split 64 VGPR + 64 AGPR and spilled ~50 regs/thread -> 52MB scratch writes
// (WRITE_SIZE 60MB), attn 98us. Fix: 256-thread blocks (4 waves x 32 queries,
// same 128 q/block), each wave walks all 2048 keys (no split-K combine), and
// __launch_bounds__(256,2) -> 256-reg cap, live set ~110 fits with slack.
// Same halved LDS-read volume as r2 (1.05M ds_read_b128 vs r1's 2.1M).
//
// In-register P: K tile rows permuted so LDS position p holds global key
// bitswap_2,3(p); QK^T C-regs are then exactly the PV B-frags in reg order.
// PV interleaved between the two QK C-tiles so only one pb pair is live.
// exp2 path: Q pre-scaled by log2e; C init = -16*log2e; raw v_exp_f32.
// XOR swizzle (octet ^ (row&7)) on staging + frag reads: conflict-free.
// LDS: 2 buf x (8K K + 8K V) = 32 KB.
// ---------------------------------------------------------------------------
__global__ __launch_bounds__(256, 2) void attn_kernel(const ushort* __restrict__ q,
                                                      const ushort* __restrict__ kb,
                                                      const ushort* __restrict__ vt,
                                                      ushort* __restrict__ out) {
    __shared__ ushort k_t[2][64 * 64];      // [buf][pos][d], permuted+swizzled
    __shared__ ushort v_t[2][64 * 64];      // [buf][d][key], swizzled

    const int i0 = blockIdx.x * 128;
    const int h0 = blockIdx.y, b = blockIdx.z;
    const int tid = threadIdx.x, w = tid >> 6, lane = tid & 63;
    const int cq = lane & 31;      // C col = query; frag row index
    const int hi = lane >> 5;      // k-half within fragment
    const int sw = cq & 7;

    union U8 { uint4 u4; short8 s8; };

    // Q B-frags: qf[dm] holds Q[q=cq][d = 16*dm + 8*hi + j]
    const ushort* qbase = q + (size_t)(b * 2048 + i0 + w * 32 + cq) * 512 + h0 * 64 + hi * 8;
    U8 qf[4];
    #pragma unroll
    for (int dm = 0; dm < 4; dm++) qf[dm].u4 = *(const uint4*)(qbase + dm * 16);

    floatx16 acc0, acc1;           // O^T tiles: d 0..31 (acc0), 32..63 (acc1)
    #pragma unroll
    for (int i = 0; i < 16; i++) { acc0[i] = 0.0f; acc1[i] = 0.0f; }
    float lsum = 0.0f;

    const ushort* kbb = kb + (size_t)b * 2048 * 64;
    const ushort* vtb = vt + (size_t)b * 64 * 2048;

    // staging: wave w covers LDS rows [16w,16w+16) via 2 calls of 8 rows;
    // lane i -> row base + (i>>3), global octet (i&7)^(row&7) (pre-swizzle).
    // K source row = bitswap_2,3(srow) (in-register-P permutation).
    const int srow0 = w * 16 + (lane >> 3);
    const int srow1 = srow0 + 8;
    const int soct = (lane & 7) ^ (srow0 & 7);
    const int prow0 = (srow0 & ~12) | ((srow0 & 4) << 1) | ((srow0 & 8) >> 1);
    const int prow1 = (srow1 & ~12) | ((srow1 & 4) << 1) | ((srow1 & 8) >> 1);
    const ushort* kgl0 = kbb + (size_t)prow0 * 64 + soct * 8;
    const ushort* kgl1 = kbb + (size_t)prow1 * 64 + soct * 8;
    const ushort* vgl0 = vtb + (size_t)srow0 * 2048 + soct * 8;
    const ushort* vgl1 = vtb + (size_t)srow1 * 2048 + soct * 8;
    ushort* kld = &k_t[0][0] + w * 1024;    // wave-uniform dest bases (buf0)
    ushort* vld = &v_t[0][0] + w * 1024;

    // per-lane swizzled octet offsets (elems), shared by K(dm) and V(slice) reads
    int koff[4];
    #pragma unroll
    for (int i = 0; i < 4; i++) koff[i] = ((2 * i + hi) ^ sw) * 8;
    const int rb0 = cq * 64, rb1 = rb0 + 2048;   // frag row bases (rows 0-31 / 32-63)

    auto stage = [&](int s, int bufo) {
        const size_t kj = (size_t)s * 4096;      // 64 keys * 64 d
        const int vj = s * 64;
        glds16(kgl0 + kj, kld + bufo);
        glds16(kgl1 + kj, kld + bufo + 512);
        glds16(vgl0 + vj, vld + bufo);
        glds16(vgl1 + vj, vld + bufo + 512);
    };

    auto compute = [&](const ushort* ktile, const ushort* vtile) {
        // --- C-tile 0 (key positions 0..31): QK^T, exp2, pack, PV ---
        {
            U8 pb0, pb1;
            floatx16 st;
            #pragma unroll
            for (int i = 0; i < 16; i++) st[i] = -23.0831206f;   // -16*log2(e)
            #pragma unroll
            for (int dm = 0; dm < 4; dm++) {
                U8 kf;
                kf.u4 = *(const uint4*)&ktile[rb0 + koff[dm]];
                st = __builtin_amdgcn_mfma_f32_32x32x16_bf16(kf.s8, qf[dm].s8, st, 0, 0, 0);
            }
            float p_[16];
            #pragma unroll
            for (int r = 0; r < 16; r++) p_[r] = __builtin_amdgcn_exp2f(st[r]);
            lsum += (((p_[0] + p_[1]) + (p_[2] + p_[3])) + ((p_[4] + p_[5]) + (p_[6] + p_[7])))
                  + (((p_[8] + p_[9]) + (p_[10] + p_[11])) + ((p_[12] + p_[13]) + (p_[14] + p_[15])));
            pb0.u4.x = pk2(p_[0], p_[1]);   pb0.u4.y = pk2(p_[2], p_[3]);
            pb0.u4.z = pk2(p_[4], p_[5]);   pb0.u4.w = pk2(p_[6], p_[7]);
            pb1.u4.x = pk2(p_[8], p_[9]);   pb1.u4.y = pk2(p_[10], p_[11]);
            pb1.u4.z = pk2(p_[12], p_[13]); pb1.u4.w = pk2(p_[14], p_[15]);
            U8 vf;
            vf.u4 = *(const uint4*)&vtile[rb0 + koff[0]];
            acc0 = __builtin_amdgcn_mfma_f32_32x32x16_bf16(vf.s8, pb0.s8, acc0, 0, 0, 0);
            vf.u4 = *(const uint4*)&vtile[rb0 + koff[1]];
            acc0 = __builtin_amdgcn_mfma_f32_32x32x16_bf16(vf.s8, pb1.s8, acc0, 0, 0, 0);
            vf.u4 = *(const uint4*)&vtile[rb1 + koff[0]];
            acc1 = __builtin_amdgcn_mfma_f32_32x32x16_bf16(vf.s8, pb0.s8, acc1, 0, 0, 0);
            vf.u4 = *(const uint4*)&vtile[rb1 + koff[1]];
            acc1 = __builtin_amdgcn_mfma_f32_32x32x16_bf16(vf.s8, pb1.s8, acc1, 0, 0, 0);
        }
        // --- C-tile 1 (key positions 32..63) ---
        {
            U8 pb2, pb3;
            floatx16 st;
            #pragma unroll
            for (int i = 0; i < 16; i++) st[i] = -23.0831206f;
            #pragma unroll
            for (int dm = 0; dm < 4; dm++) {
                U8 kf;
                kf.u4 = *(const uint4*)&ktile[rb1 + koff[dm]];
                st = __builtin_amdgcn_mfma_f32_32x32x16_bf16(kf.s8, qf[dm].s8, st, 0, 0, 0);
            }
            float p_[16];
            #pragma unroll
            for (int r = 0; r < 16; r++) p_[r] = __builtin_amdgcn_exp2f(st[r]);
            lsum += (((p_[0] + p_[1]) + (p_[2] + p_[3])) + ((p_[4] + p_[5]) + (p_[6] + p_[7])))
                  + (((p_[8] + p_[9]) + (p_[10] + p_[11])) + ((p_[12] + p_[13]) + (p_[14] + p_[15])));
            pb2.u4.x = pk2(p_[0], p_[1]);   pb2.u4.y = pk2(p_[2], p_[3]);
            pb2.u4.z = pk2(p_[4], p_[5]);   pb2.u4.w = pk2(p_[6], p_[7]);
            pb3.u4.x = pk2(p_[8], p_[9]);   pb3.u4.y = pk2(p_[10], p_[11]);
            pb3.u4.z = pk2(p_[12], p_[13]); pb3.u4.w = pk2(p_[14], p_[15]);
            U8 vf;
            vf.u4 = *(const uint4*)&vtile[rb0 + koff[2]];
            acc0 = __builtin_amdgcn_mfma_f32_32x32x16_bf16(vf.s8, pb2.s8, acc0, 0, 0, 0);
            vf.u4 = *(const uint4*)&vtile[rb0 + koff[3]];
            acc0 = __builtin_amdgcn_mfma_f32_32x32x16_bf16(vf.s8, pb3.s8, acc0, 0, 0, 0);
            vf.u4 = *(const uint4*)&vtile[rb1 + koff[2]];
            acc1 = __builtin_amdgcn_mfma_f32_32x32x16_bf16(vf.s8, pb2.s8, acc1, 0, 0, 0);
            vf.u4 = *(const uint4*)&vtile[rb1 + koff[3]];
            acc1 = __builtin_amdgcn_mfma_f32_32x32x16_bf16(vf.s8, pb3.s8, acc1, 0, 0, 0);
        }
    };

    // prologue: stage step 0 into buf0
    stage(0, 0);
    __syncthreads();

    for (int s = 0; s < 32; s++) {
        const int cur = (s & 1) << 12;          // buf elem offset: 0 / 4096
        if (s < 31) stage(s + 1, cur ^ 4096);
        compute(&k_t[0][0] + cur, &v_t[0][0] + cur);
        __syncthreads();                        // drains nxt staging; WAR on cur
    }

    lsum += __shfl_xor(lsum, 32);               // combine hi/lo key-lane halves
    float li = 1.0f / fmaxf(lsum, 1e-30f);

    // write out: reg 4t+u of acc0 -> d = u + 8t + 4hi; acc1 -> +32
    ushort* ob = out + (size_t)(b * 2048 + i0 + w * 32 + cq) * 512 + h0 * 64 + hi * 4;
    #pragma unroll
    for (int t = 0; t < 4; t++) {
        uint2 ov;
        ov.x = pk2(acc0[4 * t] * li, acc0[4 * t + 1] * li);
        ov.y = pk2(acc0[4 * t + 2] * li, acc0[4 * t + 3] * li);
        *(uint2*)(ob + t * 8) = ov;
        ov.x = pk2(acc1[4 * t] * li, acc1[4 * t + 1] * li);
        ov.y = pk2(acc1[4 * t + 2] * li, acc1[4 * t + 3] * li);
        *(uint2*)(ob + 32 + t * 8) = ov;
    }
}

// ---------------------------------------------------------------------------
// Memory plan (bf16 intermediates, ws_size needed = 16MB):
//   d_out: xn [0:16MB) (dead after gemm_qkv) -> ao [0:8MB), woT [8:16MB)
//   ws:    qb [0:8), kb [8:9), vt [9:11), wcatT [11:12.25); y [0:16) after attn.
// Dispatches (6): prep, gemm_qkv, wout_tr, attn, gemm_bt128, ln2.
// ---------------------------------------------------------------------------
extern "C" void kernel_launch(void* const* d_in, const int* in_sizes, int n_in,
                              void* d_out, int out_size, void* d_ws, size_t ws_size,
                              hipStream_t stream) {
    const void* x          = d_in[0];
    const void* norm_g     = d_in[1];
    const void* Wq         = d_in[2];
    const void* Wkv        = d_in[3];
    const void* Wout       = d_in[4];
    const void* out_norm_g = d_in[5];
    const ushort* probe = (const ushort*)d_in[0];
    ushort* ws = (ushort*)d_ws;

    const size_t M1 = 1024 * 1024 / 2;  // bf16 elems per MB
    ushort* xn    = (ushort*)d_out;
    ushort* ao    = (ushort*)d_out;
    ushort* woT   = (ushort*)((char*)d_out + (8u << 20));
    ushort* qb    = ws;
    ushort* kb    = ws + 8 * M1;
    ushort* vt    = ws + 9 * M1;
    ushort* wcatT = ws + 11 * M1;
    ushort* y     = ws;

    // prep: LN1 + Wq^T + Wkv^T fused
    prep_kernel<<<8832, 256, 0, stream>>>(x, norm_g, Wq, Wkv, xn, wcatT, probe);

    // fused q/k/v projection + l2norm + V^T
    gemm_qkv<<<dim3(10, 128), 256, 0, stream>>>(xn, wcatT, qb, kb, vt);

    // Wout^T -> d_out[8:16MB) (xn dead now)
    wout_tr_kernel<<<dim3(32, 16), 256, 0, stream>>>(Wout, woT, probe);

    // attention -> ao
    attn_kernel<<<dim3(16, 8, 4), 256, 0, stream>>>(qb, kb, vt, ao);

    // y = ao @ Wout  (128-tile, global_load_lds)
    gemm_bt128<<<dim3(8, 64), 256, 0, stream>>>(ao, woT, y, 8192, 1024, 512);

    // LN2: y -> final output
    ln2_kernel<<<8192, 256, 0, stream>>>(y, out_norm_g, d_out, probe);
}